// Round 13
// baseline (214.810 us; speedup 1.0000x reference)
//
#include <hip/hip_runtime.h>

// Problem constants: B=4, N=2048, F=D=128, H=4.
#define NB 4
#define NN 2048
#define ND 128
#define NH 4

typedef short short8 __attribute__((ext_vector_type(8)));
typedef short short4v __attribute__((ext_vector_type(4)));
typedef float floatx4 __attribute__((ext_vector_type(4)));

__device__ __forceinline__ short f2bf(float f){
  unsigned u = __float_as_uint(f);
  u += 0x7FFFu + ((u >> 16) & 1u);   // round-to-nearest-even
  return (short)(u >> 16);
}
__device__ __forceinline__ float bf2f(short s){
  unsigned u = ((unsigned)(unsigned short)s) << 16;
  return __uint_as_float(u);
}

// ---------------- K1: Xp = X @ W + bias (bf16) AND XpT = Xp^T -----------------
// (unchanged from v8 — k0's W-transpose and k1b's XpT transpose fused in)
__global__ __launch_bounds__(256) void k1_xp(const float* __restrict__ X,
                                             const float* __restrict__ W,
                                             const float* __restrict__ bias,
                                             short* __restrict__ Xp,
                                             short* __restrict__ XpT){
  int bid = blockIdx.x;                       // 128 = 4b * 32 i-tiles
  int b = bid >> 5, i0 = (bid & 31) << 6;
  int t = threadIdx.x, w = t >> 6, lane = t & 63, lq = lane >> 4, lc = lane & 15;
  __shared__ __align__(16) short ldsB[16384]; // swizzled [16 fblk][128 d][8]
  for (int k = 0; k < 64; ++k){               // transpose-convert W in-block
    int idx = k * 256 + t; int f = idx >> 7, d = idx & 127;
    ldsB[((f >> 3) * 128 + d) * 8 + (f & 7)] = f2bf(W[idx]);
  }
  short8 af[4][4];
  #pragma unroll
  for (int ib = 0; ib < 4; ++ib)
    #pragma unroll
    for (int k = 0; k < 4; ++k){
      const float* xp = &X[(b * NN + i0 + ib * 16 + lc) * ND + k * 32 + lq * 8];
      float4 x0 = *(const float4*)xp;
      float4 x1 = *(const float4*)(xp + 4);
      short8 s;
      s[0]=f2bf(x0.x); s[1]=f2bf(x0.y); s[2]=f2bf(x0.z); s[3]=f2bf(x0.w);
      s[4]=f2bf(x1.x); s[5]=f2bf(x1.y); s[6]=f2bf(x1.z); s[7]=f2bf(x1.w);
      af[ib][k] = s;
    }
  __syncthreads();
  floatx4 acc[4][2];
  #pragma unroll
  for (int ib = 0; ib < 4; ++ib)
    #pragma unroll
    for (int eb = 0; eb < 2; ++eb) acc[ib][eb] = (floatx4){0.f, 0.f, 0.f, 0.f};
  #pragma unroll
  for (int eb = 0; eb < 2; ++eb)
    #pragma unroll
    for (int k = 0; k < 4; ++k){
      short8 bf = *(short8*)&ldsB[(k * 4 + lq) * 1024 + (w * 32 + eb * 16 + lc) * 8];
      #pragma unroll
      for (int ib = 0; ib < 4; ++ib)
        acc[ib][eb] = __builtin_amdgcn_mfma_f32_16x16x32_bf16(af[ib][k], bf, acc[ib][eb], 0, 0, 0);
    }
  // all ldsB reads done -> safe to reuse the region as the transpose tile
  __syncthreads();
  short* tr = ldsB;                           // [128 d][72] (144B rows, 16B-aligned)
  #pragma unroll
  for (int ib = 0; ib < 4; ++ib)
    #pragma unroll
    for (int eb = 0; eb < 2; ++eb){
      int d = w * 32 + eb * 16 + lc;
      float bv = bias[d];
      #pragma unroll
      for (int r = 0; r < 4; ++r){
        int n = i0 + ib * 16 + lq * 4 + r;
        short s = f2bf(acc[ib][eb][r] + bv);
        Xp[(b * NN + n) * ND + d] = s;
        tr[d * 72 + (n - i0)] = s;
      }
    }
  __syncthreads();
  #pragma unroll
  for (int c = 0; c < 4; ++c){                // coalesced XpT write (k1b fused)
    int g = c * 256 + t; int d = g >> 3, n8 = g & 7;
    short8 v;
    #pragma unroll
    for (int j = 0; j < 8; ++j) v[j] = tr[d * 72 + n8 * 8 + j];
    *(short8*)&XpT[(b * ND + d) * NN + i0 + n8 * 8] = v;
  }
}

// ---------------- K2: Y[b][h] = Xp @ attn_h  (bf16 out) ---------------------------
// (unchanged from v8 — k0's attn-transpose fused in)
__global__ __launch_bounds__(256) void k2_y(const short* __restrict__ Xp,
                                            const float* __restrict__ attn,
                                            short* __restrict__ Y){
  int bid = blockIdx.x;                       // 512 = 4b * 4h * 32
  int it = bid & 31, h = (bid >> 5) & 3, b = bid >> 7;
  int i0 = it << 6;
  int t = threadIdx.x, w = t >> 6, lane = t & 63, lq = lane >> 4, lc = lane & 15;
  __shared__ __align__(16) short ldsB[16384]; // swizzled [16 dblk][128 e][8]
  const float* Asrc = attn + h * 16384;
  for (int k = 0; k < 64; ++k){               // transpose-convert attn[h] in-block
    int idx = k * 256 + t; int dd = idx >> 7, e = idx & 127;
    ldsB[((dd >> 3) * 128 + e) * 8 + (dd & 7)] = f2bf(Asrc[idx]);
  }
  short8 af[4][4];
  #pragma unroll
  for (int ib = 0; ib < 4; ++ib)
    #pragma unroll
    for (int k = 0; k < 4; ++k)
      af[ib][k] = *(const short8*)&Xp[(b * NN + i0 + ib * 16 + lc) * ND + k * 32 + lq * 8];
  __syncthreads();
  floatx4 acc[4][2];
  #pragma unroll
  for (int ib = 0; ib < 4; ++ib)
    #pragma unroll
    for (int eb = 0; eb < 2; ++eb) acc[ib][eb] = (floatx4){0.f, 0.f, 0.f, 0.f};
  #pragma unroll
  for (int eb = 0; eb < 2; ++eb)
    #pragma unroll
    for (int k = 0; k < 4; ++k){
      short8 bf = *(short8*)&ldsB[(k * 4 + lq) * 1024 + (w * 32 + eb * 16 + lc) * 8];
      #pragma unroll
      for (int ib = 0; ib < 4; ++ib)
        acc[ib][eb] = __builtin_amdgcn_mfma_f32_16x16x32_bf16(af[ib][k], bf, acc[ib][eb], 0, 0, 0);
    }
  #pragma unroll
  for (int ib = 0; ib < 4; ++ib)
    #pragma unroll
    for (int eb = 0; eb < 2; ++eb){
      int e = w * 32 + eb * 16 + lc;
      #pragma unroll
      for (int r = 0; r < 4; ++r){
        int n = i0 + ib * 16 + lq * 4 + r;
        Y[((b * NH + h) * NN + n) * ND + e] = f2bf(acc[ib][eb][r]);
      }
    }
}

// ---------------- K3 v13: barrier-free main loop, Y in LDS, 4 blocks/CU -----------
// v3's correctness-proven algebra (S^T output layout IS the K=16 MFMA A-frag ->
// each wave feeds its tanh'd P straight into PV in-register; wave-private m-strips;
// cross-wave sum once at the end) combined with v12's correctness-proven Y-in-LDS
// staging (kills v3's yf-remat/spill failure). No ldsXpT, no ldsP, NO barrier in
// the main loop -> 16 fully de-phased waves/CU, each an independent
// {A-stream || L2 loads || MFMA || tanh} pipeline.
// Register math (v11's tier law: arch cap = 256/waves_per_EU): arch ~60 <= 64 at
// (256,4); total 60 + 32 acc-AGPR = 92 <= 128 unified. LDS 32KB union -> 4 blk/CU.
// grid 2048 = (ms 4, b 4, 128 i-tiles of 16 rows). Each block: m-range ms*512..+512.
__global__ __launch_bounds__(256, 4) void k3_fused(const short* __restrict__ Xp,
                                                   const short* __restrict__ XpT,
                                                   const short* __restrict__ Y,
                                                   const float* __restrict__ A,
                                                   float* __restrict__ part){
  int bid = blockIdx.x;
  int it = bid & 127, b = (bid >> 7) & 3, ms = bid >> 9;
  int i0 = it << 4;
  int t = threadIdx.x, w = t >> 6, lane = t & 63, lq = lane >> 4, lc = lane & 15;

  // 32KB union: ldsY (16KB swizzled bf16) during loop; red (32KB f32) at epilogue
  __shared__ __align__(16) char smem[32768];
  short* ldsY = (short*)smem;

  // stage Y[b][4h][i0..i0+16][128] -> LDS, XOR-swizzle 16B chunk with (i&7)  [v12]
  #pragma unroll
  for (int c = 0; c < 4; ++c){
    int slot = c * 256 + t;
    int h = slot >> 8, i = (slot >> 4) & 15, d8 = slot & 15;
    short8 v = *(const short8*)&Y[((b * NH + h) * NN + i0 + i) * ND + d8 * 8];
    *(short8*)&ldsY[h * 2048 + i * 128 + ((d8 ^ (i & 7)) << 3)] = v;
  }
  __syncthreads();                            // the only pre-epilogue barrier

  floatx4 acc[8];                             // acc[dt] = part[i=lq*4+r][d=dt*16+lc]
  #pragma unroll
  for (int dt = 0; dt < 8; ++dt) acc[dt] = (floatx4){0.f,0.f,0.f,0.f};

  const int mbase = ms << 9;                  // 512 m per block, 16/wave/iter
  const float* arow = &A[(size_t)(b * NN + i0 + lc) * NN];

  for (int itn = 0; itn < 8; ++itn){
    int m0 = mbase + itn * 64 + w * 16;       // this wave's private 16-m strip

    // S^T A-frags: Xp rows m0..m0+15 (L2-resident)
    short8 xpf[4];
    const short* xr = Xp + (b * NN + m0 + lc) * ND;
    #pragma unroll
    for (int k = 0; k < 4; ++k) xpf[k] = *(const short8*)&xr[k * 32 + lq * 8];

    // PV B-frags: XpT[d][m0..m0+15]; lane holds B[k=lq*4+j][col=d=dt*16+lc] (8B)
    short4v xt[8];
    #pragma unroll
    for (int dt = 0; dt < 8; ++dt)
      xt[dt] = *(const short4v*)&XpT[(b * ND + dt * 16 + lc) * NN + m0 + lq * 4];

    // adjacency for this strip (rows i0+lc, cols m0+lq*4..+4)
    floatx4 av = *(const floatx4*)&arow[m0 + lq * 4];

    // S^T per head (Y B-frags from swizzled LDS), tanh, head-mean in-register
    float psum[4] = {0.f, 0.f, 0.f, 0.f};
    #pragma unroll
    for (int h = 0; h < 4; ++h){
      floatx4 S = (floatx4){0.f,0.f,0.f,0.f};
      #pragma unroll
      for (int k = 0; k < 4; ++k){
        short8 yfr = *(short8*)&ldsY[h * 2048 + lc * 128 + (((k * 4 + lq) ^ (lc & 7)) << 3)];
        S = __builtin_amdgcn_mfma_f32_16x16x32_bf16(xpf[k], yfr, S, 0, 0, 0);
      }
      #pragma unroll
      for (int r = 0; r < 4; ++r){
        float x = av[r] * S[r];
        float e = __builtin_amdgcn_exp2f(x * 2.885390081777926f);  // e^{2x}
        psum[r] += 1.f - 2.f * __builtin_amdgcn_rcpf(e + 1.f);     // tanh
      }
    }

    // P -> bf16 hi/lo split; psum[r] IS the K=16 A-frag element j=r  [v3-proven]
    short4v hi4, lo4;
    #pragma unroll
    for (int r = 0; r < 4; ++r){
      float pb = 0.25f * psum[r];
      short h16 = f2bf(pb);
      hi4[r] = h16;
      lo4[r] = f2bf(pb - bf2f(h16));
    }

    // PV: acc[dt] += (Phi + Plo) @ Xp over this strip's 16 m (K=16 MFMA, in-reg)
    #pragma unroll
    for (int dt = 0; dt < 8; ++dt){
      acc[dt] = __builtin_amdgcn_mfma_f32_16x16x16bf16_1k(hi4, xt[dt], acc[dt], 0, 0, 0);
      acc[dt] = __builtin_amdgcn_mfma_f32_16x16x16bf16_1k(lo4, xt[dt], acc[dt], 0, 0, 0);
    }
  }

  // epilogue: cross-wave sum via LDS overlay (v3-proven), coalesced store
  __syncthreads();                            // all waves done reading ldsY
  float* red = (float*)smem;                  // red[w][i][d] = w*2048 + i*128 + d
  #pragma unroll
  for (int dt = 0; dt < 8; ++dt)
    #pragma unroll
    for (int r = 0; r < 4; ++r)
      red[w * 2048 + (lq * 4 + r) * 128 + dt * 16 + lc] = acc[dt][r];
  __syncthreads();
  float* dst = part + (size_t)ms * 1048576 + (size_t)(b * NN + i0) * ND;
  #pragma unroll
  for (int j = 0; j < 8; ++j){
    int idx = j * 256 + t;                    // idx = i*128 + d, coalesced
    dst[idx] = red[idx] + red[2048 + idx] + red[4096 + idx] + red[6144 + idx];
  }
}

// ---------------- K4: out = relu(relu(Σ ms-partials) + X) -------------------------
__global__ void k4_final(const float* __restrict__ part, const float* __restrict__ X,
                         float* __restrict__ out){
  int f = (blockIdx.x * 256 + threadIdx.x) * 4;
  float4 s0 = *(const float4*)(part + f);
  float4 s1 = *(const float4*)(part + 1048576 + f);
  float4 s2 = *(const float4*)(part + 2097152 + f);
  float4 s3 = *(const float4*)(part + 3145728 + f);
  float4 xv = *(const float4*)(X + f);
  float4 o;
  o.x = fmaxf(fmaxf(s0.x + s1.x + s2.x + s3.x, 0.f) + xv.x, 0.f);
  o.y = fmaxf(fmaxf(s0.y + s1.y + s2.y + s3.y, 0.f) + xv.y, 0.f);
  o.z = fmaxf(fmaxf(s0.z + s1.z + s2.z + s3.z, 0.f) + xv.z, 0.f);
  o.w = fmaxf(fmaxf(s0.w + s1.w + s2.w + s3.w, 0.f) + xv.w, 0.f);
  *(float4*)(out + f) = o;
}

// ---------------- launch ----------------------------------------------------------
extern "C" void kernel_launch(void* const* d_in, const int* in_sizes, int n_in,
                              void* d_out, int out_size, void* d_ws, size_t ws_size,
                              hipStream_t stream) {
  const float* X    = (const float*)d_in[0];   // [4,2048,128]
  const float* A    = (const float*)d_in[1];   // [4,2048,2048]
  const float* W    = (const float*)d_in[2];   // [128,128]
  const float* bias = (const float*)d_in[3];   // [128]
  const float* attn = (const float*)d_in[4];   // [4,128,128]
  float* out = (float*)d_out;

  // workspace layout
  const size_t OFF_XP    = 0;                          // 2 MB bf16
  const size_t OFF_XPT   = (size_t)2 << 20;            // 2 MB bf16
  const size_t OFF_Y     = (size_t)4 << 20;            // 8 MB bf16
  const size_t OFF_PART  = (size_t)12 << 20;           // 16 MB f32 (4 partials)
  const size_t NEED = (size_t)28 << 20;
  if (ws_size < NEED) return;

  char* ws = (char*)d_ws;
  short* Xp    = (short*)(ws + OFF_XP);
  short* XpT   = (short*)(ws + OFF_XPT);
  short* Y     = (short*)(ws + OFF_Y);
  float* part  = (float*)(ws + OFF_PART);

  k1_xp<<<128, 256, 0, stream>>>(X, W, bias, Xp, XpT);
  k2_y<<<512, 256, 0, stream>>>(Xp, attn, Y);
  k3_fused<<<2048, 256, 0, stream>>>(Xp, XpT, Y, A, part);
  k4_final<<<1024, 256, 0, stream>>>(part, X, out);
}

// Round 14
// 166.429 us; speedup vs baseline: 1.2907x; 1.2907x over previous
//
#include <hip/hip_runtime.h>

// Problem constants: B=4, N=2048, F=D=128, H=4.
#define NB 4
#define NN 2048
#define ND 128
#define NH 4

typedef short short8 __attribute__((ext_vector_type(8)));
typedef short short4v __attribute__((ext_vector_type(4)));
typedef float floatx4 __attribute__((ext_vector_type(4)));

__device__ __forceinline__ short f2bf(float f){
  unsigned u = __float_as_uint(f);
  u += 0x7FFFu + ((u >> 16) & 1u);   // round-to-nearest-even
  return (short)(u >> 16);
}
__device__ __forceinline__ float bf2f(short s){
  unsigned u = ((unsigned)(unsigned short)s) << 16;
  return __uint_as_float(u);
}

// ---------------- K1: Xp = X @ W + bias (bf16) AND XpT = Xp^T -----------------
// v14: #pragma unroll 16 on the W-conversion loop — 16 loads in flight instead of
// one dependent load per iteration (k1 runs at 0.5 blocks/CU; nothing else hides
// the per-load latency).
__global__ __launch_bounds__(256) void k1_xp(const float* __restrict__ X,
                                             const float* __restrict__ W,
                                             const float* __restrict__ bias,
                                             short* __restrict__ Xp,
                                             short* __restrict__ XpT){
  int bid = blockIdx.x;                       // 128 = 4b * 32 i-tiles
  int b = bid >> 5, i0 = (bid & 31) << 6;
  int t = threadIdx.x, w = t >> 6, lane = t & 63, lq = lane >> 4, lc = lane & 15;
  __shared__ __align__(16) short ldsB[16384]; // swizzled [16 fblk][128 d][8]
  #pragma unroll 16
  for (int k = 0; k < 64; ++k){               // transpose-convert W in-block
    int idx = k * 256 + t; int f = idx >> 7, d = idx & 127;
    ldsB[((f >> 3) * 128 + d) * 8 + (f & 7)] = f2bf(W[idx]);
  }
  short8 af[4][4];
  #pragma unroll
  for (int ib = 0; ib < 4; ++ib)
    #pragma unroll
    for (int k = 0; k < 4; ++k){
      const float* xp = &X[(b * NN + i0 + ib * 16 + lc) * ND + k * 32 + lq * 8];
      float4 x0 = *(const float4*)xp;
      float4 x1 = *(const float4*)(xp + 4);
      short8 s;
      s[0]=f2bf(x0.x); s[1]=f2bf(x0.y); s[2]=f2bf(x0.z); s[3]=f2bf(x0.w);
      s[4]=f2bf(x1.x); s[5]=f2bf(x1.y); s[6]=f2bf(x1.z); s[7]=f2bf(x1.w);
      af[ib][k] = s;
    }
  __syncthreads();
  floatx4 acc[4][2];
  #pragma unroll
  for (int ib = 0; ib < 4; ++ib)
    #pragma unroll
    for (int eb = 0; eb < 2; ++eb) acc[ib][eb] = (floatx4){0.f, 0.f, 0.f, 0.f};
  #pragma unroll
  for (int eb = 0; eb < 2; ++eb)
    #pragma unroll
    for (int k = 0; k < 4; ++k){
      short8 bf = *(short8*)&ldsB[(k * 4 + lq) * 1024 + (w * 32 + eb * 16 + lc) * 8];
      #pragma unroll
      for (int ib = 0; ib < 4; ++ib)
        acc[ib][eb] = __builtin_amdgcn_mfma_f32_16x16x32_bf16(af[ib][k], bf, acc[ib][eb], 0, 0, 0);
    }
  // all ldsB reads done -> safe to reuse the region as the transpose tile
  __syncthreads();
  short* tr = ldsB;                           // [128 d][72] (144B rows, 16B-aligned)
  #pragma unroll
  for (int ib = 0; ib < 4; ++ib)
    #pragma unroll
    for (int eb = 0; eb < 2; ++eb){
      int d = w * 32 + eb * 16 + lc;
      float bv = bias[d];
      #pragma unroll
      for (int r = 0; r < 4; ++r){
        int n = i0 + ib * 16 + lq * 4 + r;
        short s = f2bf(acc[ib][eb][r] + bv);
        Xp[(b * NN + n) * ND + d] = s;
        tr[d * 72 + (n - i0)] = s;
      }
    }
  __syncthreads();
  #pragma unroll
  for (int c = 0; c < 4; ++c){                // coalesced XpT write (k1b fused)
    int g = c * 256 + t; int d = g >> 3, n8 = g & 7;
    short8 v;
    #pragma unroll
    for (int j = 0; j < 8; ++j) v[j] = tr[d * 72 + n8 * 8 + j];
    *(short8*)&XpT[(b * ND + d) * NN + i0 + n8 * 8] = v;
  }
}

// ---------------- K2: Y[b][h] = Xp @ attn_h  (bf16 out) ---------------------------
// v14: #pragma unroll 16 on the attn-conversion loop (same latency argument; k2
// runs at 2 blocks/CU).
__global__ __launch_bounds__(256) void k2_y(const short* __restrict__ Xp,
                                            const float* __restrict__ attn,
                                            short* __restrict__ Y){
  int bid = blockIdx.x;                       // 512 = 4b * 4h * 32
  int it = bid & 31, h = (bid >> 5) & 3, b = bid >> 7;
  int i0 = it << 6;
  int t = threadIdx.x, w = t >> 6, lane = t & 63, lq = lane >> 4, lc = lane & 15;
  __shared__ __align__(16) short ldsB[16384]; // swizzled [16 dblk][128 e][8]
  const float* Asrc = attn + h * 16384;
  #pragma unroll 16
  for (int k = 0; k < 64; ++k){               // transpose-convert attn[h] in-block
    int idx = k * 256 + t; int dd = idx >> 7, e = idx & 127;
    ldsB[((dd >> 3) * 128 + e) * 8 + (dd & 7)] = f2bf(Asrc[idx]);
  }
  short8 af[4][4];
  #pragma unroll
  for (int ib = 0; ib < 4; ++ib)
    #pragma unroll
    for (int k = 0; k < 4; ++k)
      af[ib][k] = *(const short8*)&Xp[(b * NN + i0 + ib * 16 + lc) * ND + k * 32 + lq * 8];
  __syncthreads();
  floatx4 acc[4][2];
  #pragma unroll
  for (int ib = 0; ib < 4; ++ib)
    #pragma unroll
    for (int eb = 0; eb < 2; ++eb) acc[ib][eb] = (floatx4){0.f, 0.f, 0.f, 0.f};
  #pragma unroll
  for (int eb = 0; eb < 2; ++eb)
    #pragma unroll
    for (int k = 0; k < 4; ++k){
      short8 bf = *(short8*)&ldsB[(k * 4 + lq) * 1024 + (w * 32 + eb * 16 + lc) * 8];
      #pragma unroll
      for (int ib = 0; ib < 4; ++ib)
        acc[ib][eb] = __builtin_amdgcn_mfma_f32_16x16x32_bf16(af[ib][k], bf, acc[ib][eb], 0, 0, 0);
    }
  #pragma unroll
  for (int ib = 0; ib < 4; ++ib)
    #pragma unroll
    for (int eb = 0; eb < 2; ++eb){
      int e = w * 32 + eb * 16 + lc;
      #pragma unroll
      for (int r = 0; r < 4; ++r){
        int n = i0 + ib * 16 + lq * 4 + r;
        Y[((b * NH + h) * NN + n) * ND + e] = f2bf(acc[ib][eb][r]);
      }
    }
}

// ---------------- K3 v12 (UNCHANGED — best-known, 65us, passing) ------------------
// Y in XOR-swizzled LDS (register-tier law: arch cap = 256/waves_per_EU; Y-in-LDS
// is what makes the 4-block tier legal). Single-buffered ldsXpT/P, two barriers/
// iter. v13's barrier-free variant regressed (110us): block-cooperative staging +
// P-sharing + K=32 PV beats per-wave independence on this problem.
__global__ __launch_bounds__(256, 4) void k3_fused(const short* __restrict__ Xp,
                                                   const short* __restrict__ XpT,
                                                   const short* __restrict__ Y,
                                                   const float* __restrict__ A,
                                                   float* __restrict__ part){
  int bid = blockIdx.x;
  int it = bid & 127, b = (bid >> 7) & 3, ms = bid >> 9;
  int i0 = it << 4;
  int t = threadIdx.x, w = t >> 6, lane = t & 63, lq = lane >> 4, lc = lane & 15;

  __shared__ __align__(16) short ldsY[8192];       // [4 h][16 i][128 d], swizzled
  __shared__ __align__(16) short ldsXpT[8320];     // [8 mb][128 d][8], stride 1040
  __shared__ __align__(16) short ldsPh[1024];      // [8 mb][16 i][8]
  __shared__ __align__(16) short ldsPl[1024];

  // stage Y[b][4h][i0..i0+16][128] -> LDS, XOR-swizzle 16B chunk with (i&7)
  #pragma unroll
  for (int c = 0; c < 4; ++c){
    int slot = c * 256 + t;
    int h = slot >> 8, i = (slot >> 4) & 15, d8 = slot & 15;
    short8 v = *(const short8*)&Y[((b * NH + h) * NN + i0 + i) * ND + d8 * 8];
    *(short8*)&ldsY[h * 2048 + i * 128 + ((d8 ^ (i & 7)) << 3)] = v;
  }

  floatx4 acc[2];
  acc[0] = (floatx4){0.f,0.f,0.f,0.f};
  acc[1] = (floatx4){0.f,0.f,0.f,0.f};

  const int mbase = ms << 9;                       // 512 m per block
  const int poff = (w * 2 + (lq >> 1)) * 128 + lc * 8 + (lq & 1) * 4;

  __syncthreads();                                 // ldsY ready

  for (int itn = 0; itn < 8; ++itn){
    int m0 = mbase + itn * 64;
    if (itn) __syncthreads();                      // barrier A: prev PV reads done
    // stage XpT slice [128 d][64 m] -> swizzled LDS (coalesced 128B/row-group)
    const short* src = XpT + b * (ND * NN) + m0;
    #pragma unroll
    for (int c = 0; c < 4; ++c){
      int q = c * 256 + t; int d = q >> 3, mb = q & 7;
      *(short8*)&ldsXpT[mb * 1040 + d * 8] = *(const short8*)&src[d * NN + mb * 8];
    }
    // Xp A-frags for S^T, direct from global (L2-resident)
    short8 xpf[4];
    const short* xr = Xp + (b * NN + m0 + w * 16 + lc) * ND;
    #pragma unroll
    for (int k = 0; k < 4; ++k) xpf[k] = *(const short8*)&xr[k * 32 + lq * 8];
    // adjacency: one float4 per lane covers this wave's 4 m-rows at col i0+lc
    floatx4 av = *(const floatx4*)&A[(size_t)(b * NN + i0 + lc) * NN + m0 + w * 16 + lq * 4];

    // S^T per head (Y B-frags from swizzled LDS), tanh, head-mean in-register
    float psum[4] = {0.f, 0.f, 0.f, 0.f};
    #pragma unroll
    for (int h = 0; h < 4; ++h){
      floatx4 S = (floatx4){0.f,0.f,0.f,0.f};
      #pragma unroll
      for (int k = 0; k < 4; ++k){
        short8 yfr = *(short8*)&ldsY[h * 2048 + lc * 128 + (((k * 4 + lq) ^ (lc & 7)) << 3)];
        S = __builtin_amdgcn_mfma_f32_16x16x32_bf16(xpf[k], yfr, S, 0, 0, 0);
      }
      #pragma unroll
      for (int r = 0; r < 4; ++r){
        float x = av[r] * S[r];
        float e = __builtin_amdgcn_exp2f(x * 2.885390081777926f);  // e^{2x}
        psum[r] += 1.f - 2.f * __builtin_amdgcn_rcpf(e + 1.f);     // tanh
      }
    }
    short4v hi4, lo4;
    #pragma unroll
    for (int r = 0; r < 4; ++r){
      float pb = 0.25f * psum[r];
      short h16 = f2bf(pb);
      hi4[r] = h16;
      lo4[r] = f2bf(pb - bf2f(h16));
    }
    *(short4v*)&ldsPh[poff] = hi4;
    *(short4v*)&ldsPl[poff] = lo4;
    __syncthreads();                               // barrier B: stage + P visible

    // PV: acc += (Phi + Plo) @ Xp ; wave w owns d-range [w*32, w*32+32)
    #pragma unroll
    for (int kb = 0; kb < 2; ++kb){
      short8 ph = *(short8*)&ldsPh[(kb * 4 + lq) * 128 + lc * 8];
      short8 pl = *(short8*)&ldsPl[(kb * 4 + lq) * 128 + lc * 8];
      #pragma unroll
      for (int db = 0; db < 2; ++db){
        short8 bfr = *(short8*)&ldsXpT[(kb * 4 + lq) * 1040 + (w * 32 + db * 16 + lc) * 8];
        acc[db] = __builtin_amdgcn_mfma_f32_16x16x32_bf16(ph, bfr, acc[db], 0, 0, 0);
        acc[db] = __builtin_amdgcn_mfma_f32_16x16x32_bf16(pl, bfr, acc[db], 0, 0, 0);
      }
    }
  }
  // epilogue: partial (per-ms) tile, mean factor already folded into Pbar
  float* dst = part + (size_t)ms * 1048576 + (b * NN + i0) * ND;
  #pragma unroll
  for (int db = 0; db < 2; ++db)
    #pragma unroll
    for (int r = 0; r < 4; ++r)
      dst[(lq * 4 + r) * ND + w * 32 + db * 16 + lc] = acc[db][r];
}

// ---------------- K4: out = relu(relu(Σ ms-partials) + X) -------------------------
__global__ void k4_final(const float* __restrict__ part, const float* __restrict__ X,
                         float* __restrict__ out){
  int f = (blockIdx.x * 256 + threadIdx.x) * 4;
  float4 s0 = *(const float4*)(part + f);
  float4 s1 = *(const float4*)(part + 1048576 + f);
  float4 s2 = *(const float4*)(part + 2097152 + f);
  float4 s3 = *(const float4*)(part + 3145728 + f);
  float4 xv = *(const float4*)(X + f);
  float4 o;
  o.x = fmaxf(fmaxf(s0.x + s1.x + s2.x + s3.x, 0.f) + xv.x, 0.f);
  o.y = fmaxf(fmaxf(s0.y + s1.y + s2.y + s3.y, 0.f) + xv.y, 0.f);
  o.z = fmaxf(fmaxf(s0.z + s1.z + s2.z + s3.z, 0.f) + xv.z, 0.f);
  o.w = fmaxf(fmaxf(s0.w + s1.w + s2.w + s3.w, 0.f) + xv.w, 0.f);
  *(float4*)(out + f) = o;
}

// ---------------- launch ----------------------------------------------------------
extern "C" void kernel_launch(void* const* d_in, const int* in_sizes, int n_in,
                              void* d_out, int out_size, void* d_ws, size_t ws_size,
                              hipStream_t stream) {
  const float* X    = (const float*)d_in[0];   // [4,2048,128]
  const float* A    = (const float*)d_in[1];   // [4,2048,2048]
  const float* W    = (const float*)d_in[2];   // [128,128]
  const float* bias = (const float*)d_in[3];   // [128]
  const float* attn = (const float*)d_in[4];   // [4,128,128]
  float* out = (float*)d_out;

  // workspace layout
  const size_t OFF_XP    = 0;                          // 2 MB bf16
  const size_t OFF_XPT   = (size_t)2 << 20;            // 2 MB bf16
  const size_t OFF_Y     = (size_t)4 << 20;            // 8 MB bf16
  const size_t OFF_PART  = (size_t)12 << 20;           // 16 MB f32 (4 partials)
  const size_t NEED = (size_t)28 << 20;
  if (ws_size < NEED) return;

  char* ws = (char*)d_ws;
  short* Xp    = (short*)(ws + OFF_XP);
  short* XpT   = (short*)(ws + OFF_XPT);
  short* Y     = (short*)(ws + OFF_Y);
  float* part  = (float*)(ws + OFF_PART);

  k1_xp<<<128, 256, 0, stream>>>(X, W, bias, Xp, XpT);
  k2_y<<<512, 256, 0, stream>>>(Xp, attn, Y);
  k3_fused<<<2048, 256, 0, stream>>>(Xp, XpT, Y, A, part);
  k4_final<<<1024, 256, 0, stream>>>(part, X, out);
}

// Round 15
// 163.484 us; speedup vs baseline: 1.3140x; 1.0180x over previous
//
#include <hip/hip_runtime.h>

// Problem constants: B=4, N=2048, F=D=128, H=4.
#define NB 4
#define NN 2048
#define ND 128
#define NH 4

typedef short short8 __attribute__((ext_vector_type(8)));
typedef short short4v __attribute__((ext_vector_type(4)));
typedef float floatx4 __attribute__((ext_vector_type(4)));

__device__ __forceinline__ short f2bf(float f){
  unsigned u = __float_as_uint(f);
  u += 0x7FFFu + ((u >> 16) & 1u);   // round-to-nearest-even
  return (short)(u >> 16);
}
__device__ __forceinline__ float bf2f(short s){
  unsigned u = ((unsigned)(unsigned short)s) << 16;
  return __uint_as_float(u);
}

// ---------------- K1: Xp = X @ W + bias (bf16) AND XpT = Xp^T -----------------
// (v14: unroll 16 on the W-conversion loop)
__global__ __launch_bounds__(256) void k1_xp(const float* __restrict__ X,
                                             const float* __restrict__ W,
                                             const float* __restrict__ bias,
                                             short* __restrict__ Xp,
                                             short* __restrict__ XpT){
  int bid = blockIdx.x;                       // 128 = 4b * 32 i-tiles
  int b = bid >> 5, i0 = (bid & 31) << 6;
  int t = threadIdx.x, w = t >> 6, lane = t & 63, lq = lane >> 4, lc = lane & 15;
  __shared__ __align__(16) short ldsB[16384]; // swizzled [16 fblk][128 d][8]
  #pragma unroll 16
  for (int k = 0; k < 64; ++k){               // transpose-convert W in-block
    int idx = k * 256 + t; int f = idx >> 7, d = idx & 127;
    ldsB[((f >> 3) * 128 + d) * 8 + (f & 7)] = f2bf(W[idx]);
  }
  short8 af[4][4];
  #pragma unroll
  for (int ib = 0; ib < 4; ++ib)
    #pragma unroll
    for (int k = 0; k < 4; ++k){
      const float* xp = &X[(b * NN + i0 + ib * 16 + lc) * ND + k * 32 + lq * 8];
      float4 x0 = *(const float4*)xp;
      float4 x1 = *(const float4*)(xp + 4);
      short8 s;
      s[0]=f2bf(x0.x); s[1]=f2bf(x0.y); s[2]=f2bf(x0.z); s[3]=f2bf(x0.w);
      s[4]=f2bf(x1.x); s[5]=f2bf(x1.y); s[6]=f2bf(x1.z); s[7]=f2bf(x1.w);
      af[ib][k] = s;
    }
  __syncthreads();
  floatx4 acc[4][2];
  #pragma unroll
  for (int ib = 0; ib < 4; ++ib)
    #pragma unroll
    for (int eb = 0; eb < 2; ++eb) acc[ib][eb] = (floatx4){0.f, 0.f, 0.f, 0.f};
  #pragma unroll
  for (int eb = 0; eb < 2; ++eb)
    #pragma unroll
    for (int k = 0; k < 4; ++k){
      short8 bf = *(short8*)&ldsB[(k * 4 + lq) * 1024 + (w * 32 + eb * 16 + lc) * 8];
      #pragma unroll
      for (int ib = 0; ib < 4; ++ib)
        acc[ib][eb] = __builtin_amdgcn_mfma_f32_16x16x32_bf16(af[ib][k], bf, acc[ib][eb], 0, 0, 0);
    }
  // all ldsB reads done -> safe to reuse the region as the transpose tile
  __syncthreads();
  short* tr = ldsB;                           // [128 d][72] (144B rows, 16B-aligned)
  #pragma unroll
  for (int ib = 0; ib < 4; ++ib)
    #pragma unroll
    for (int eb = 0; eb < 2; ++eb){
      int d = w * 32 + eb * 16 + lc;
      float bv = bias[d];
      #pragma unroll
      for (int r = 0; r < 4; ++r){
        int n = i0 + ib * 16 + lq * 4 + r;
        short s = f2bf(acc[ib][eb][r] + bv);
        Xp[(b * NN + n) * ND + d] = s;
        tr[d * 72 + (n - i0)] = s;
      }
    }
  __syncthreads();
  #pragma unroll
  for (int c = 0; c < 4; ++c){                // coalesced XpT write (k1b fused)
    int g = c * 256 + t; int d = g >> 3, n8 = g & 7;
    short8 v;
    #pragma unroll
    for (int j = 0; j < 8; ++j) v[j] = tr[d * 72 + n8 * 8 + j];
    *(short8*)&XpT[(b * ND + d) * NN + i0 + n8 * 8] = v;
  }
}

// ---------------- K2: Y[b][h] = Xp @ attn_h  (bf16 out) ---------------------------
// (v14: unroll 16 on the attn-conversion loop)
__global__ __launch_bounds__(256) void k2_y(const short* __restrict__ Xp,
                                            const float* __restrict__ attn,
                                            short* __restrict__ Y){
  int bid = blockIdx.x;                       // 512 = 4b * 4h * 32
  int it = bid & 31, h = (bid >> 5) & 3, b = bid >> 7;
  int i0 = it << 6;
  int t = threadIdx.x, w = t >> 6, lane = t & 63, lq = lane >> 4, lc = lane & 15;
  __shared__ __align__(16) short ldsB[16384]; // swizzled [16 dblk][128 e][8]
  const float* Asrc = attn + h * 16384;
  #pragma unroll 16
  for (int k = 0; k < 64; ++k){               // transpose-convert attn[h] in-block
    int idx = k * 256 + t; int dd = idx >> 7, e = idx & 127;
    ldsB[((dd >> 3) * 128 + e) * 8 + (dd & 7)] = f2bf(Asrc[idx]);
  }
  short8 af[4][4];
  #pragma unroll
  for (int ib = 0; ib < 4; ++ib)
    #pragma unroll
    for (int k = 0; k < 4; ++k)
      af[ib][k] = *(const short8*)&Xp[(b * NN + i0 + ib * 16 + lc) * ND + k * 32 + lq * 8];
  __syncthreads();
  floatx4 acc[4][2];
  #pragma unroll
  for (int ib = 0; ib < 4; ++ib)
    #pragma unroll
    for (int eb = 0; eb < 2; ++eb) acc[ib][eb] = (floatx4){0.f, 0.f, 0.f, 0.f};
  #pragma unroll
  for (int eb = 0; eb < 2; ++eb)
    #pragma unroll
    for (int k = 0; k < 4; ++k){
      short8 bf = *(short8*)&ldsB[(k * 4 + lq) * 1024 + (w * 32 + eb * 16 + lc) * 8];
      #pragma unroll
      for (int ib = 0; ib < 4; ++ib)
        acc[ib][eb] = __builtin_amdgcn_mfma_f32_16x16x32_bf16(af[ib][k], bf, acc[ib][eb], 0, 0, 0);
    }
  #pragma unroll
  for (int ib = 0; ib < 4; ++ib)
    #pragma unroll
    for (int eb = 0; eb < 2; ++eb){
      int e = w * 32 + eb * 16 + lc;
      #pragma unroll
      for (int r = 0; r < 4; ++r){
        int n = i0 + ib * 16 + lq * 4 + r;
        Y[((b * NH + h) * NN + n) * ND + e] = f2bf(acc[ib][eb][r]);
      }
    }
}

// ---------------- K3 v15: 2 i-tiles per block — amortize stage+barriers ----------
// v12's proven structure (Y-in-LDS, single-buffer ldsXpT, two barriers/iter), but
// each block owns TWO adjacent 16-row i-tiles (32 rows). Per iteration: the XpT
// stage (16.6KB) and both barriers are UNCHANGED but feed 48 MFMAs instead of 24;
// xpf (S^T A-frags, same m-rows) is shared across tiles (Xp L2 traffic halves);
// PV's bfr B-frag is read once and consumed by both tiles' P. LDS 57.6KB -> 2
// blocks/CU (8 waves, 2/EU -> arch cap 128, ~80 live: spill-free by the tier law).
// grid 1024 = (ms 4, b 4, 64 i-pairs of 32 rows). Each block: m-range ms*512..+512.
__global__ __launch_bounds__(256, 2) void k3_fused(const short* __restrict__ Xp,
                                                   const short* __restrict__ XpT,
                                                   const short* __restrict__ Y,
                                                   const float* __restrict__ A,
                                                   float* __restrict__ part){
  int bid = blockIdx.x;
  int it = bid & 63, b = (bid >> 6) & 3, ms = bid >> 8;
  int i0 = it << 5;                                // 32 rows per block
  int t = threadIdx.x, w = t >> 6, lane = t & 63, lq = lane >> 4, lc = lane & 15;

  __shared__ __align__(16) short ldsY[16384];      // [2 tl][4 h][16 i][128 d], swz
  __shared__ __align__(16) short ldsXpT[8320];     // [8 mb][128 d][8], stride 1040
  __shared__ __align__(16) short ldsPh[2][1024];   // [tl][8 mb][16 i][8]
  __shared__ __align__(16) short ldsPl[2][1024];

  // stage Y for both tiles -> LDS, XOR-swizzle 16B chunk with (i&7)
  #pragma unroll
  for (int c = 0; c < 8; ++c){
    int slot = c * 256 + t;                        // 2048 slots of 16B
    int tl = slot >> 10, h = (slot >> 8) & 3, i = (slot >> 4) & 15, d8 = slot & 15;
    short8 v = *(const short8*)&Y[((b * NH + h) * NN + i0 + tl * 16 + i) * ND + d8 * 8];
    *(short8*)&ldsY[tl * 8192 + h * 2048 + i * 128 + ((d8 ^ (i & 7)) << 3)] = v;
  }

  floatx4 acc[2][2];                               // [tile][db]
  #pragma unroll
  for (int tl = 0; tl < 2; ++tl)
    #pragma unroll
    for (int db = 0; db < 2; ++db) acc[tl][db] = (floatx4){0.f,0.f,0.f,0.f};

  const int mbase = ms << 9;                       // 512 m per block
  const int poff = (w * 2 + (lq >> 1)) * 128 + lc * 8 + (lq & 1) * 4;

  __syncthreads();                                 // ldsY ready

  for (int itn = 0; itn < 8; ++itn){
    int m0 = mbase + itn * 64;
    if (itn) __syncthreads();                      // barrier A: prev PV reads done
    // stage XpT slice [128 d][64 m] -> swizzled LDS (coalesced 128B/row-group)
    const short* src = XpT + b * (ND * NN) + m0;
    #pragma unroll
    for (int c = 0; c < 4; ++c){
      int q = c * 256 + t; int d = q >> 3, mb = q & 7;
      *(short8*)&ldsXpT[mb * 1040 + d * 8] = *(const short8*)&src[d * NN + mb * 8];
    }
    // Xp A-frags for S^T, direct from global (L2-resident) — SHARED by both tiles
    short8 xpf[4];
    const short* xr = Xp + (b * NN + m0 + w * 16 + lc) * ND;
    #pragma unroll
    for (int k = 0; k < 4; ++k) xpf[k] = *(const short8*)&xr[k * 32 + lq * 8];
    // adjacency: one float4 per lane per tile
    floatx4 av[2];
    #pragma unroll
    for (int tl = 0; tl < 2; ++tl)
      av[tl] = *(const floatx4*)&A[(size_t)(b * NN + i0 + tl * 16 + lc) * NN
                                   + m0 + w * 16 + lq * 4];

    // S^T per tile per head (Y from swizzled LDS), tanh, head-mean in-register
    #pragma unroll
    for (int tl = 0; tl < 2; ++tl){
      float psum[4] = {0.f, 0.f, 0.f, 0.f};
      #pragma unroll
      for (int h = 0; h < 4; ++h){
        floatx4 S = (floatx4){0.f,0.f,0.f,0.f};
        #pragma unroll
        for (int k = 0; k < 4; ++k){
          short8 yfr = *(short8*)&ldsY[tl * 8192 + h * 2048 + lc * 128
                                       + (((k * 4 + lq) ^ (lc & 7)) << 3)];
          S = __builtin_amdgcn_mfma_f32_16x16x32_bf16(xpf[k], yfr, S, 0, 0, 0);
        }
        #pragma unroll
        for (int r = 0; r < 4; ++r){
          float x = av[tl][r] * S[r];
          float e = __builtin_amdgcn_exp2f(x * 2.885390081777926f);  // e^{2x}
          psum[r] += 1.f - 2.f * __builtin_amdgcn_rcpf(e + 1.f);     // tanh
        }
      }
      short4v hi4, lo4;
      #pragma unroll
      for (int r = 0; r < 4; ++r){
        float pb = 0.25f * psum[r];
        short h16 = f2bf(pb);
        hi4[r] = h16;
        lo4[r] = f2bf(pb - bf2f(h16));
      }
      *(short4v*)&ldsPh[tl][poff] = hi4;
      *(short4v*)&ldsPl[tl][poff] = lo4;
    }
    __syncthreads();                               // barrier B: stage + P visible

    // PV: acc[tl] += (Phi + Plo) @ Xp ; bfr read ONCE per (kb,db), used by both
    #pragma unroll
    for (int kb = 0; kb < 2; ++kb){
      short8 ph0 = *(short8*)&ldsPh[0][(kb * 4 + lq) * 128 + lc * 8];
      short8 pl0 = *(short8*)&ldsPl[0][(kb * 4 + lq) * 128 + lc * 8];
      short8 ph1 = *(short8*)&ldsPh[1][(kb * 4 + lq) * 128 + lc * 8];
      short8 pl1 = *(short8*)&ldsPl[1][(kb * 4 + lq) * 128 + lc * 8];
      #pragma unroll
      for (int db = 0; db < 2; ++db){
        short8 bfr = *(short8*)&ldsXpT[(kb * 4 + lq) * 1040 + (w * 32 + db * 16 + lc) * 8];
        acc[0][db] = __builtin_amdgcn_mfma_f32_16x16x32_bf16(ph0, bfr, acc[0][db], 0, 0, 0);
        acc[0][db] = __builtin_amdgcn_mfma_f32_16x16x32_bf16(pl0, bfr, acc[0][db], 0, 0, 0);
        acc[1][db] = __builtin_amdgcn_mfma_f32_16x16x32_bf16(ph1, bfr, acc[1][db], 0, 0, 0);
        acc[1][db] = __builtin_amdgcn_mfma_f32_16x16x32_bf16(pl1, bfr, acc[1][db], 0, 0, 0);
      }
    }
  }
  // epilogue: partial (per-ms) tiles, mean factor already folded into Pbar
  #pragma unroll
  for (int tl = 0; tl < 2; ++tl){
    float* dst = part + (size_t)ms * 1048576 + (size_t)(b * NN + i0 + tl * 16) * ND;
    #pragma unroll
    for (int db = 0; db < 2; ++db)
      #pragma unroll
      for (int r = 0; r < 4; ++r)
        dst[(lq * 4 + r) * ND + w * 32 + db * 16 + lc] = acc[tl][db][r];
  }
}

// ---------------- K4: out = relu(relu(Σ ms-partials) + X) -------------------------
__global__ void k4_final(const float* __restrict__ part, const float* __restrict__ X,
                         float* __restrict__ out){
  int f = (blockIdx.x * 256 + threadIdx.x) * 4;
  float4 s0 = *(const float4*)(part + f);
  float4 s1 = *(const float4*)(part + 1048576 + f);
  float4 s2 = *(const float4*)(part + 2097152 + f);
  float4 s3 = *(const float4*)(part + 3145728 + f);
  float4 xv = *(const float4*)(X + f);
  float4 o;
  o.x = fmaxf(fmaxf(s0.x + s1.x + s2.x + s3.x, 0.f) + xv.x, 0.f);
  o.y = fmaxf(fmaxf(s0.y + s1.y + s2.y + s3.y, 0.f) + xv.y, 0.f);
  o.z = fmaxf(fmaxf(s0.z + s1.z + s2.z + s3.z, 0.f) + xv.z, 0.f);
  o.w = fmaxf(fmaxf(s0.w + s1.w + s2.w + s3.w, 0.f) + xv.w, 0.f);
  *(float4*)(out + f) = o;
}

// ---------------- launch ----------------------------------------------------------
extern "C" void kernel_launch(void* const* d_in, const int* in_sizes, int n_in,
                              void* d_out, int out_size, void* d_ws, size_t ws_size,
                              hipStream_t stream) {
  const float* X    = (const float*)d_in[0];   // [4,2048,128]
  const float* A    = (const float*)d_in[1];   // [4,2048,2048]
  const float* W    = (const float*)d_in[2];   // [128,128]
  const float* bias = (const float*)d_in[3];   // [128]
  const float* attn = (const float*)d_in[4];   // [4,128,128]
  float* out = (float*)d_out;

  // workspace layout
  const size_t OFF_XP    = 0;                          // 2 MB bf16
  const size_t OFF_XPT   = (size_t)2 << 20;            // 2 MB bf16
  const size_t OFF_Y     = (size_t)4 << 20;            // 8 MB bf16
  const size_t OFF_PART  = (size_t)12 << 20;           // 16 MB f32 (4 partials)
  const size_t NEED = (size_t)28 << 20;
  if (ws_size < NEED) return;

  char* ws = (char*)d_ws;
  short* Xp    = (short*)(ws + OFF_XP);
  short* XpT   = (short*)(ws + OFF_XPT);
  short* Y     = (short*)(ws + OFF_Y);
  float* part  = (float*)(ws + OFF_PART);

  k1_xp<<<128, 256, 0, stream>>>(X, W, bias, Xp, XpT);
  k2_y<<<512, 256, 0, stream>>>(Xp, attn, Y);
  k3_fused<<<1024, 256, 0, stream>>>(Xp, XpT, Y, A, part);
  k4_final<<<1024, 256, 0, stream>>>(part, X, out);
}